// Round 18
// baseline (234.300 us; speedup 1.0000x reference)
//
#include <hip/hip_runtime.h>
#include <hip/hip_bf16.h>
#include <stdint.h>

#define NB 32
#define NS 2048
#define ND 1024
#define NA 1024
#define MASK_NEG 1e30f

#define BM 256
#define BN 256
#define BK 64
#define NTILES 64  // 4 a-tiles x 16 K-tiles

typedef __attribute__((ext_vector_type(4))) float f32x4;
typedef __attribute__((ext_vector_type(16))) float f32x16;
typedef __attribute__((ext_vector_type(8))) __bf16 bf16x8;

__device__ __forceinline__ void glds16(const void* g, void* l) {
  __builtin_amdgcn_global_load_lds(
      (const __attribute__((address_space(1))) uint32_t*)g,
      (__attribute__((address_space(3))) uint32_t*)(uintptr_t)l, 16, 0, 0);
}

// ---------------- zero scores (atomic accumulation target) ----------------
__global__ void zero_f32(float* __restrict__ p, int n) {
  int i = blockIdx.x * 256 + threadIdx.x;
  if (i < n) p[i] = 0.f;
}

// ---------------- fp32 -> bf16 bulk convert (W2 only, 2 MB) ----------------
__global__ __launch_bounds__(256) void cvt_bf16(const float* __restrict__ in,
                                                __bf16* __restrict__ out, int n8) {
  long i = blockIdx.x * 256 + threadIdx.x;
  const long stride = (long)gridDim.x * 256;
  for (; i < n8; i += stride) {
    f32x4 a = ((const f32x4*)in)[2 * i];
    f32x4 b = ((const f32x4*)in)[2 * i + 1];
    bf16x8 o;
#pragma unroll
    for (int j = 0; j < 4; ++j) { o[j] = (__bf16)a[j]; o[4 + j] = (__bf16)b[j]; }
    ((bf16x8*)out)[i] = o;
  }
}

// ---------------- w1q[b,a] = query[b,:] . W1[a,:]  (fp32) ----------------
__global__ __launch_bounds__(256) void w1q_kernel(const float* __restrict__ q,
                                                  const float* __restrict__ W1,
                                                  float* __restrict__ w1q) {
  const int b = blockIdx.x;
  const int a0 = blockIdx.y * 64;
  const int t = threadIdx.x;
  const int al = t >> 2;
  const int part = t & 3;
  const float* wrow = W1 + (size_t)(a0 + al) * ND + part * 256;
  const float* qrow = q + (size_t)b * ND + part * 256;
  float sum = 0.f;
#pragma unroll 8
  for (int i = 0; i < 256; i += 4) {
    float4 w = *reinterpret_cast<const float4*>(wrow + i);
    float4 x = *reinterpret_cast<const float4*>(qrow + i);
    sum += w.x * x.x + w.y * x.y + w.z * x.z + w.w * x.w;
  }
  __shared__ float red[256];
  red[t] = sum;
  __syncthreads();
  if (t < 64) {
    w1q[(size_t)b * NA + a0 + t] = red[t * 4] + red[t * 4 + 1] + red[t * 4 + 2] + red[t * 4 + 3];
  }
}

// ---------------- fused scores GEMM: fp32-direct A, 4Mx2N, 32x32x16 MFMA ----------------
// R16 base unchanged (fp32 keys staged straight to LDS; A fp32 quarters
// ring-6 slot (4T+q)%6; B bf16 halves ring-4 slot (2T+h)%4; 160 KB LDS;
// 4Mx2N waves; 4-phase schedule, all A-frag reads at ph1, vmcnt(0) at ph4).
// ONE change: MFMA shape 16x16x32 -> 32x32x16. Same data volume and read
// count; MFMA floor -17% (4096 vs 3378 FLOP/cyc, m119) and instruction count
// halves (32 vs 64 per wave per K-tile).
// Operand layouts (HW-verified m74/m101 lineage): A row = l&31, k=(l>>5)*8+j;
// B col = l&31 (a-dim), k=(l>>5)*8+j; C/D col = l&31, row = (r&3)+8*(r>>2)+4*(l>>5).
// Phase ks (0..3): stage -> [ks==0: all 16 A-frag reads + cvt] -> 4 B-frags
// (unit (ks*2+hi)^(row&7)) -> BAR -> lgkm(0) -> 8 MFMA -> [ks==3: vmcnt(0)] -> BAR.
__global__ __launch_bounds__(512, 1) void score_gemm(
    const float* __restrict__ keysf, const __bf16* __restrict__ W2b,
    const float* __restrict__ w1q, const float* __restrict__ vvec,
    float* __restrict__ scores) {
  __shared__ __attribute__((aligned(1024))) char ldsA[6 * 16384];  // 96 KB fp32 quarters
  __shared__ __attribute__((aligned(1024))) char ldsB[4 * 16384];  // 64 KB bf16 halves

  const int t = threadIdx.x;
  const int bs0 = blockIdx.x * BM;
  const int b = bs0 >> 11;  // / NS
  const int lane = t & 63;
  const int wid = t >> 6;
  const int wr = wid >> 1;   // 0..3: 64-row quarter of output (= A quarter)
  const int wc = wid & 1;    // 0..1: 128-col half of output (= B half)
  const int r31 = lane & 31;
  const int hi = lane >> 5;
  const int lrA = r31 & 15;  // A-row swizzle key (rows mi*32+r31: &15 == r31&15)
  const int lrB = r31 & 7;   // B-row swizzle key

  // staging maps (thread-linear LDS dest, inverse-swizzled global source) -- R16-verified
  const int rowA = t >> 4;
  const int scolA = (t & 15) ^ (rowA & 15);
  const int rowB = t >> 3;
  const int scolB = (t & 7) ^ (rowB & 7);

  f32x16 acc[2][4];
#pragma unroll
  for (int mi = 0; mi < 2; ++mi)
#pragma unroll
    for (int nt = 0; nt < 4; ++nt)
#pragma unroll
      for (int r = 0; r < 16; ++r) acc[mi][nt][r] = 0.f;

  bf16x8 af[2][4], bfr[4];

#define STAGE_A(T, Q)                                                           \
  do {                                                                          \
    if ((T) < NTILES) {                                                         \
      const unsigned slot_ = (4u * (unsigned)(T) + (unsigned)(Q)) % 6u;         \
      char* d_ = ldsA + slot_ * 16384 + t * 16;                                 \
      const size_t r0_ = (size_t)(bs0 + (Q)*64 + rowA);                         \
      const int kf_ = ((T)&15) * 64 + scolA * 4;                                \
      glds16(keysf + r0_ * ND + kf_, d_);                                       \
      glds16(keysf + (r0_ + 32) * ND + kf_, d_ + 8192);                         \
    }                                                                           \
  } while (0)

#define STAGE_B(T, H)                                                           \
  do {                                                                          \
    if ((T) < NTILES) {                                                         \
      const unsigned slot_ = (2u * (unsigned)(T) + (unsigned)(H)) % 4u;         \
      char* d_ = ldsB + slot_ * 16384 + t * 16;                                 \
      const size_t r0_ = (size_t)(((T) >> 4) * 256 + (H)*128 + rowB);           \
      const int ke_ = (((T)&15) * 64) + scolB * 8;                              \
      glds16(W2b + r0_ * ND + ke_, d_);                                         \
      glds16(W2b + (r0_ + 64) * ND + ke_, d_ + 8192);                           \
    }                                                                           \
  } while (0)

#define SB_ __builtin_amdgcn_sched_barrier(0)
#define P1 __builtin_amdgcn_s_setprio(1)
#define P0 __builtin_amdgcn_s_setprio(0)
#define BAR __builtin_amdgcn_s_barrier()

#define PHASE(KS_, STAGES)                                                      \
  do {                                                                          \
    STAGES;                                                                     \
    if ((KS_) == 0) {                                                           \
      const char* Ab_ = ldsA + ((4u * (unsigned)tau + (unsigned)wr) % 6u) * 16384; \
      _Pragma("unroll") for (int mi = 0; mi < 2; ++mi) {                        \
        const int rb_ = (mi * 32 + r31) * 256;                                  \
        _Pragma("unroll") for (int ks = 0; ks < 4; ++ks) {                      \
          const int u0_ = ks * 4 + hi * 2;                                      \
          f32x4 l0 = *reinterpret_cast<const f32x4*>(Ab_ + rb_ + (u0_ ^ lrA) * 16); \
          f32x4 l1 = *reinterpret_cast<const f32x4*>(Ab_ + rb_ + ((u0_ + 1) ^ lrA) * 16); \
          _Pragma("unroll") for (int j = 0; j < 4; ++j) {                       \
            af[mi][ks][j] = (__bf16)l0[j];                                      \
            af[mi][ks][4 + j] = (__bf16)l1[j];                                  \
          }                                                                     \
        }                                                                       \
      }                                                                         \
    }                                                                           \
    {                                                                           \
      const char* Bb_ = ldsB + ((2u * (unsigned)tau + (unsigned)wc) % 4u) * 16384; \
      _Pragma("unroll") for (int nt = 0; nt < 4; ++nt) {                        \
        const int rb_ = (nt * 32 + r31) * 128;                                  \
        bfr[nt] = *reinterpret_cast<const bf16x8*>(                             \
            Bb_ + rb_ + (((KS_)*2 + hi) ^ lrB) * 16);                           \
      }                                                                         \
    }                                                                           \
    BAR;                                                                        \
    asm volatile("s_waitcnt lgkmcnt(0)");                                       \
    SB_;                                                                        \
    P1;                                                                         \
    _Pragma("unroll") for (int mi = 0; mi < 2; ++mi)                            \
        _Pragma("unroll") for (int nt = 0; nt < 4; ++nt)                        \
            acc[mi][nt] = __builtin_amdgcn_mfma_f32_32x32x16_bf16(              \
                af[mi][(KS_)], bfr[nt], acc[mi][nt], 0, 0, 0);                  \
    P0;                                                                         \
    if ((KS_) == 3) {                                                           \
      asm volatile("s_waitcnt vmcnt(0)");                                       \
      SB_;                                                                      \
    }                                                                           \
    BAR;                                                                        \
  } while (0)

  // ---- prologue: full tile 0; drain once ----
  STAGE_A(0, 0);
  STAGE_A(0, 1);
  STAGE_A(0, 2);
  STAGE_A(0, 3);
  STAGE_B(0, 0);
  STAGE_B(0, 1);
  __syncthreads();

  for (int tau = 0; tau < NTILES; ++tau) {
    PHASE(0, { STAGE_A(tau + 1, 0); STAGE_A(tau + 1, 1); STAGE_B(tau + 1, 0); });
    PHASE(1, { STAGE_A(tau + 1, 2); STAGE_A(tau + 1, 3); STAGE_B(tau + 1, 1); });
    PHASE(2, {});
    PHASE(3, {});  // + vmcnt(0)

    // ---- per-a-tile epilogue: tanh + v-weight -> atomic scores ----
    // C/D: col(a) = r31, row(bs) = mi*32 + (r&3) + 8*(r>>2) + 4*hi
    if ((tau & 15) == 15) {
      const int a0 = (tau >> 4) * BN;
      float w1v[4], vv[4];
#pragma unroll
      for (int nt = 0; nt < 4; ++nt) {
        const int a = a0 + wc * 128 + nt * 32 + r31;
        w1v[nt] = w1q[(size_t)b * NA + a];
        vv[nt] = vvec[a];
      }
#pragma unroll
      for (int mi = 0; mi < 2; ++mi) {
#pragma unroll
        for (int r = 0; r < 16; ++r) {
          float p = 0.f;
#pragma unroll
          for (int nt = 0; nt < 4; ++nt) {
            const float x = acc[mi][nt][r] + w1v[nt];
            const float e = __expf(2.f * x);
            p += (1.f - 2.f * __builtin_amdgcn_rcpf(e + 1.f)) * vv[nt];
          }
          p += __shfl_xor(p, 1);
          p += __shfl_xor(p, 2);
          p += __shfl_xor(p, 4);
          p += __shfl_xor(p, 8);
          p += __shfl_xor(p, 16);
          if (r31 == 0)
            atomicAdd(&scores[bs0 + wr * 64 + mi * 32 + (r & 3) + 8 * (r >> 2) + 4 * hi], p);
        }
#pragma unroll
        for (int nt = 0; nt < 4; ++nt)
#pragma unroll
          for (int r = 0; r < 16; ++r) acc[mi][nt][r] = 0.f;
      }
    }
  }

#undef STAGE_A
#undef STAGE_B
#undef PHASE
#undef SB_
#undef P1
#undef P0
#undef BAR
}

// ---------------- masked softmax ----------------
__global__ __launch_bounds__(256) void softmax_kernel(const float* __restrict__ scores,
                                                      const int* __restrict__ mask,
                                                      float* __restrict__ out) {
  const int b = blockIdx.x;
  const int t = threadIdx.x;
  float sc[8];
  float mx = -3.4e38f;
#pragma unroll
  for (int j = 0; j < 8; ++j) {
    int i = t + j * 256;
    float s = scores[b * NS + i];
    if (mask[b * NS + i] == 0) s -= MASK_NEG;
    sc[j] = s;
    mx = fmaxf(mx, s);
  }
#pragma unroll
  for (int off = 1; off < 64; off <<= 1) mx = fmaxf(mx, __shfl_xor(mx, off));
  __shared__ float redm[4];
  __shared__ float reds[4];
  if ((t & 63) == 0) redm[t >> 6] = mx;
  __syncthreads();
  mx = fmaxf(fmaxf(redm[0], redm[1]), fmaxf(redm[2], redm[3]));
  float e[8];
  float sum = 0.f;
#pragma unroll
  for (int j = 0; j < 8; ++j) {
    e[j] = __expf(sc[j] - mx);
    sum += e[j];
  }
#pragma unroll
  for (int off = 1; off < 64; off <<= 1) sum += __shfl_xor(sum, off);
  if ((t & 63) == 0) reds[t >> 6] = sum;
  __syncthreads();
  sum = reds[0] + reds[1] + reds[2] + reds[3];
  float inv = 1.f / sum;
#pragma unroll
  for (int j = 0; j < 8; ++j) out[b * NS + t + j * 256] = e[j] * inv;
}

extern "C" void kernel_launch(void* const* d_in, const int* in_sizes, int n_in,
                              void* d_out, int out_size, void* d_ws, size_t ws_size,
                              hipStream_t stream) {
  const float* q = (const float*)d_in[0];
  const float* keysf = (const float*)d_in[1];
  const int* mask = (const int*)d_in[2];
  const float* W1 = (const float*)d_in[3];
  const float* W2f = (const float*)d_in[4];
  const float* v = (const float*)d_in[5];
  float* out = (float*)d_out;

  float* scores = (float*)d_ws;                                 // 256 KB
  float* w1q = scores + NB * NS;                                // 128 KB
  __bf16* W2b = (__bf16*)(w1q + NB * NA);                       // 2 MB

  zero_f32<<<NB * NS / 256, 256, 0, stream>>>(scores, NB * NS);
  cvt_bf16<<<512, 256, 0, stream>>>(W2f, W2b, NA * ND / 8);
  w1q_kernel<<<dim3(NB, NA / 64), 256, 0, stream>>>(q, W1, w1q);
  score_gemm<<<NB * NS / BM, 512, 0, stream>>>(keysf, W2b, w1q, v, scores);
  softmax_kernel<<<NB, 256, 0, stream>>>(scores, mask, out);
}